// Round 1
// 957.853 us; speedup vs baseline: 1.4747x; 1.4747x over previous
//
#include <hip/hip_runtime.h>

// 3x3 stride-1 pad-1 conv, NCHW fp32 in/out, per-tap MFMA f16.
// B=8, CIN=COUT=16, H=W=1024.
//
// v2: 16-row x 64-px tile per block (was 1 row x 256 px).
//  - halo amortization: staged rows / output rows = 18/16 = 1.125 (was 3.0)
//  - div-free staging decode (shifts only), float4 global loads,
//    cin-paired f16x2 LDS writes
//  - A-fragment reuse across output rows: each staged row read once per
//    wave (3 kw frags), feeding 3 rotating accumulators (kh=0/1/2 roles)
//    -> 54 ds_read_b64 per thread instead of 144
//
// LDS layout [18][66][20] halfs, cin innermost (pad 16->20 halfs = 40B px
// stride: 8B-aligned ds_read_b64 A-frags, ~uniform bank spread).
//
// MFMA 16x16x16 f16 mapping (verified in v1):
//   A[m=lane&15][k=4*(lane>>4)+j]   m = pixel-in-tile, k = cin
//   B[k][n=lane&15]                 n = cout
//   D[row=m=4*(lane>>4)+reg][col=n=lane&15] -> float4 store, cout=ln

typedef _Float16 f16x4 __attribute__((ext_vector_type(4)));
typedef _Float16 f16x2 __attribute__((ext_vector_type(2)));
typedef float f32x4 __attribute__((ext_vector_type(4)));

#define B_N    8
#define C_IN   16
#define C_OUT  16
#define H_N    1024
#define W_N    1024
#define TILE_W 64
#define TILE_H 16
#define LDS_R  (TILE_H + 2)   // 18 staged rows
#define LDS_W  (TILE_W + 2)   // 66 staged cols
#define CPAD   20             // 16 cin + 4 pad halfs -> 40B per pixel

__global__ __launch_bounds__(256, 3) void conv3x3_mfma(
    const float* __restrict__ x, const float* __restrict__ wt,
    float* __restrict__ out)
{
    __shared__ _Float16 s_x[LDS_R][LDS_W][CPAD];

    const int w0   = blockIdx.x * TILE_W;   // 0..960
    const int h0   = blockIdx.y * TILE_H;   // 0..1008
    const int b    = blockIdx.z;
    const int tid  = threadIdx.x;
    const int lane = tid & 63;
    const int q    = lane >> 4;             // 0..3
    const int ln   = lane & 15;             // 0..15
    const int wave = tid >> 6;              // 0..3
    const int seg  = wave * 16;             // wave's 16-pixel segment

    // ---- stage interior: 18 rows x 16 cin x 64 px ----
    // pair-elements: r(18) x cinpair(8) x float4(16) = 2304 = 9*256
    // flat bits: [3:0]=i4  [6:4]=cp  [11:7]=r   (shifts only, no divides)
#pragma unroll
    for (int it = 0; it < 9; ++it) {
        const int flat = tid + 256 * it;
        const int i4 = flat & 15;
        const int cp = (flat >> 4) & 7;
        const int r  = flat >> 7;
        const int gh = h0 - 1 + r;
        const int gw = w0 + 4 * i4;
        f32x4 va = {0.f, 0.f, 0.f, 0.f};
        f32x4 vb = {0.f, 0.f, 0.f, 0.f};
        if ((unsigned)gh < (unsigned)H_N) {
            const size_t base =
                (((size_t)b * C_IN + 2 * cp) * H_N + gh) * W_N + gw;
            va = *(const f32x4*)&x[base];
            vb = *(const f32x4*)&x[base + (size_t)H_N * W_N];
        }
#pragma unroll
        for (int j = 0; j < 4; ++j) {
            f16x2 p;
            p[0] = (_Float16)va[j];
            p[1] = (_Float16)vb[j];
            *(f16x2*)&s_x[r][1 + 4 * i4 + j][2 * cp] = p;
        }
    }

    // ---- stage halo columns: r(18) x cinpair(8) x side(2) = 288 ----
#pragma unroll
    for (int it = 0; it < 2; ++it) {
        const int f2 = tid + 256 * it;
        if (f2 < 288) {
            const int side = f2 & 1;
            const int cp   = (f2 >> 1) & 7;
            const int r    = f2 >> 4;
            const int i    = side ? (LDS_W - 1) : 0;   // 0 or 65
            const int gw   = w0 - 1 + i;               // w0-1 or w0+64
            const int gh   = h0 - 1 + r;
            float a = 0.f, c2 = 0.f;
            if ((unsigned)gh < (unsigned)H_N && (unsigned)gw < (unsigned)W_N) {
                const size_t base =
                    (((size_t)b * C_IN + 2 * cp) * H_N + gh) * W_N + gw;
                a  = x[base];
                c2 = x[base + (size_t)H_N * W_N];
            }
            f16x2 p;
            p[0] = (_Float16)a;
            p[1] = (_Float16)c2;
            *(f16x2*)&s_x[r][i][2 * cp] = p;
        }
    }

    // ---- B fragments: 9 taps, in registers (overlaps staging latency) ----
    f16x4 bfrag[9];
#pragma unroll
    for (int kh = 0; kh < 3; ++kh) {
#pragma unroll
        for (int kw = 0; kw < 3; ++kw) {
            f16x4 f;
#pragma unroll
            for (int j = 0; j < 4; ++j) {
                const int cin = 4 * q + j;
                f[j] = (_Float16)wt[((ln * C_IN + cin) * 3 + kh) * 3 + kw];
            }
            bfrag[kh * 3 + kw] = f;
        }
    }

    __syncthreads();

    // ---- compute: walk 18 staged rows once; 3 rotating accumulators ----
    // staged row ir feeds output rows r = ir (kh=0), ir-1 (kh=1), ir-2 (kh=2).
    // Full unroll -> all acc[] indices compile-time (no scratch, rule #20).
    f32x4 acc[3];
    const size_t outbase = ((size_t)b * C_OUT + ln) * H_N;
#pragma unroll
    for (int ir = 0; ir < LDS_R; ++ir) {
        const f16x4 a0 = *(const f16x4*)&s_x[ir][seg + ln + 0][4 * q];
        const f16x4 a1 = *(const f16x4*)&s_x[ir][seg + ln + 1][4 * q];
        const f16x4 a2 = *(const f16x4*)&s_x[ir][seg + ln + 2][4 * q];

        if (ir <= TILE_H - 1) {            // kh=0: open row r=ir
            f32x4 t = {0.f, 0.f, 0.f, 0.f};
            t = __builtin_amdgcn_mfma_f32_16x16x16f16(a0, bfrag[0], t, 0, 0, 0);
            t = __builtin_amdgcn_mfma_f32_16x16x16f16(a1, bfrag[1], t, 0, 0, 0);
            t = __builtin_amdgcn_mfma_f32_16x16x16f16(a2, bfrag[2], t, 0, 0, 0);
            acc[ir % 3] = t;
        }
        if (ir >= 1 && ir - 1 <= TILE_H - 1) {   // kh=1: row r=ir-1
            f32x4 t = acc[(ir - 1) % 3];
            t = __builtin_amdgcn_mfma_f32_16x16x16f16(a0, bfrag[3], t, 0, 0, 0);
            t = __builtin_amdgcn_mfma_f32_16x16x16f16(a1, bfrag[4], t, 0, 0, 0);
            t = __builtin_amdgcn_mfma_f32_16x16x16f16(a2, bfrag[5], t, 0, 0, 0);
            acc[(ir - 1) % 3] = t;
        }
        if (ir >= 2) {                     // kh=2: close row r=ir-2, store
            const int r = ir - 2;
            f32x4 t = acc[r % 3];
            t = __builtin_amdgcn_mfma_f32_16x16x16f16(a0, bfrag[6], t, 0, 0, 0);
            t = __builtin_amdgcn_mfma_f32_16x16x16f16(a1, bfrag[7], t, 0, 0, 0);
            t = __builtin_amdgcn_mfma_f32_16x16x16f16(a2, bfrag[8], t, 0, 0, 0);
            const int wout = w0 + seg + 4 * q;
            *(f32x4*)&out[(outbase + (h0 + r)) * W_N + wout] = t;
        }
    }
}

extern "C" void kernel_launch(void* const* d_in, const int* in_sizes, int n_in,
                              void* d_out, int out_size, void* d_ws, size_t ws_size,
                              hipStream_t stream) {
    const float* x  = (const float*)d_in[0];
    const float* wt = (const float*)d_in[1];
    float* out = (float*)d_out;
    dim3 grid(W_N / TILE_W, H_N / TILE_H, B_N);
    conv3x3_mfma<<<grid, 256, 0, stream>>>(x, wt, out);
}